// Round 14
// baseline (389.572 us; speedup 1.0000x reference)
//
#include <hip/hip_runtime.h>

#define BASE_BITS 17
#define BUCKET_LOG 16
#define NBUCKETS (1u << BUCKET_LOG)      // 65536 buckets x 4 slots x 4B = 1MB/table
#define NSLOTS (NBUCKETS * 4u)
#define EMPTY 0xFFFFFFFFu
#define MAGIC_BAD 0x600DF00D

#define NB 64u                            // build blocks = bucket windows
#define WBUCK (NBUCKETS / NB)             // 1024 buckets per window
#define WSLOTS (WBUCK * 4u)               // 4096 slots per window (16KB)

typedef int  iv4 __attribute__((ext_vector_type(4)));
typedef unsigned uv4 __attribute__((ext_vector_type(4)));

__device__ __forceinline__ unsigned bucket_of(unsigned k) {
    return (k * 2654435761u) >> (32 - BUCKET_LOG);
}
// advance one bucket, wrapping within the 1024-bucket window
__device__ __forceinline__ unsigned bnext(unsigned b) {
    return (b & ~(WBUCK - 1u)) | ((b + 1u) & (WBUCK - 1u));
}

// Pure-register bucket match; >=0 hit slot, -2 miss, -1 continue.
__device__ __forceinline__ int match4(uv4 q, unsigned e, unsigned b) {
    int slot = -1;
    slot = (q.w == e) ? (int)(b * 4u + 3u) : slot;
    slot = (q.z == e) ? (int)(b * 4u + 2u) : slot;
    slot = (q.y == e) ? (int)(b * 4u + 1u) : slot;
    slot = (q.x == e) ? (int)(b * 4u + 0u) : slot;
    if (slot >= 0) return slot;
    unsigned mx = max(max(q.x, q.y), max(q.z, q.w));  // EMPTY is max u32
    return (mx == EMPTY) ? -2 : -1;
}

// Flags: flags[0]!=0 => int64 layout (plain-stored by builder/detector);
//        flags[2]==MAGIC_BAD => tables unusable -> int32 bsearch fallback.
__global__ void detect_dtype_kernel(const unsigned* __restrict__ xw,
                                    int* __restrict__ flags) {
    __shared__ int nz;
    if (threadIdx.x == 0) nz = 0;
    __syncthreads();
    if (xw[2 * threadIdx.x + 1] != 0u) atomicOr(&nz, 1);
    __syncthreads();
    if (threadIdx.x == 0) { flags[0] = nz ? 0 : ~0; flags[2] = MAGIC_BAD; }
}

// ---------------- fused clear+build: LDS window tables, no grid sync -------
__global__ __launch_bounds__(256) void fused_build_kernel(
    const int* __restrict__ keys2, const int* __restrict__ vals2, int n2,
    const int* __restrict__ keys3, const int* __restrict__ vals3, int n3,
    const unsigned* __restrict__ xw,
    unsigned* __restrict__ K2, int* __restrict__ V2,
    unsigned* __restrict__ K3, int* __restrict__ V3,
    int* __restrict__ flags)
{
    __shared__ unsigned lk2[WSLOTS];   // 16KB
    __shared__ unsigned lk3[WSLOTS];   // 16KB
    __shared__ int nz;
    int tid = threadIdx.x;

    if (blockIdx.x == 0) {             // dtype detect (block-uniform branch)
        if (tid == 0) nz = 0;
        __syncthreads();
        if (xw[2 * tid + 1] != 0u) atomicOr(&nz, 1);
        __syncthreads();
        if (tid == 0) flags[0] = nz ? 0 : ~0;
    }

    for (unsigned i = tid; i < WSLOTS; i += 256u) { lk2[i] = EMPTY; lk3[i] = EMPTY; }
    __syncthreads();

    unsigned blo = blockIdx.x * WBUCK;         // first bucket of my window
    int ntot = n2 + n3;
    for (int i = tid; i < ntot; i += 256) {    // full scan, keep my window's keys
        bool is2 = (i < n2);
        const int* keys = is2 ? keys2 : keys3;
        const int* vals = is2 ? vals2 : vals3;
        unsigned* lk    = is2 ? lk2 : lk3;
        int* Vg         = is2 ? V2 : V3;
        int idx = is2 ? i : (i - n2);
        unsigned k = (unsigned)keys[idx];
        if (k == EMPTY) { flags[2] = MAGIC_BAD; continue; }  // sentinel clash
        unsigned h = bucket_of(k);
        if (h - blo < WBUCK) {
            unsigned s = (h - blo) * 4u;
            for (;;) {
                if (atomicCAS(&lk[s], EMPTY, k) == EMPTY) {   // LDS CAS: CU-local
                    Vg[blo * 4u + s] = vals[idx];             // plain global store
                    break;
                }
                s = (s + 1u) & (WSLOTS - 1u);                 // wrap within window
            }
        }
    }
    __syncthreads();

    uv4* gk2 = (uv4*)(K2 + blo * 4u);
    uv4* gk3 = (uv4*)(K3 + blo * 4u);
    for (unsigned i = tid; i < WSLOTS / 4u; i += 256u) {      // coalesced write-out
        gk2[i] = ((uv4*)lk2)[i];
        gk3[i] = ((uv4*)lk3)[i];
    }
}

// ---------------- binary-search fallback helpers ---------------------------
template <typename K>
__device__ __forceinline__ int lower_bound(const K* __restrict__ keys, int n, K key) {
    int lo = 0, hi = n;
    while (lo < hi) {
        int mid = (lo + hi) >> 1;
        if (keys[mid] < key) lo = mid + 1; else hi = mid;
    }
    return lo;
}

template <typename K>
__device__ __forceinline__ K bprobe(const K* __restrict__ keys,
                                    const K* __restrict__ vals, int n, K key) {
    int idx = lower_bound(keys, n, key);
    if (idx >= n) idx = n - 1;
    return (keys[idx] == key) ? vals[idx] : (K)0;
}

// ---------------- main lookup: 4 elems/thread, 8 forced-parallel probes ----
__global__ __launch_bounds__(256) void ngram_hash_kernel(
    const void* __restrict__ xv,
    const unsigned* __restrict__ K2, const int* __restrict__ V2,
    const unsigned* __restrict__ K3, const int* __restrict__ V3,
    const void* __restrict__ k2v, const void* __restrict__ v2v,
    const void* __restrict__ k3v, const void* __restrict__ v3v,
    void* __restrict__ outv,
    int n2, int n3, int S, int total, const int* __restrict__ flags)
{
    int gid = blockIdx.x * blockDim.x + threadIdx.x;
    int base = gid * 4;
    if (base >= total) return;
    int f0 = flags[0], f2 = flags[2];

    if (f0 != 0) {
        // int64 layout (x64-enabled harness): binary-search path
        const long long* x = (const long long*)xv;
        long long* out = (long long*)outv;
        for (int i = 0; i < 4 && base + i < total; ++i) {
            int g = base + i;
            int s = g & (S - 1);
            long long t2 = x[g];
            long long t1 = (s >= 1) ? x[g - 1] : 0ll;
            long long t0 = (s >= 2) ? x[g - 2] : 0ll;
            long long e2 = (t1 << BASE_BITS) | t2;
            long long e3 = (((t0 << BASE_BITS) | t1) << BASE_BITS) | t2;
            out[g]         = bprobe((const long long*)k2v, (const long long*)v2v, n2, e2);
            out[total + g] = bprobe((const long long*)k3v, (const long long*)v3v, n3, e3);
        }
        return;
    }
    if (f2 == MAGIC_BAD) {
        // hash tables unusable: int32 binary search
        const int* x = (const int*)xv;
        int* out = (int*)outv;
        for (int i = 0; i < 4 && base + i < total; ++i) {
            int g = base + i;
            int s = g & (S - 1);
            unsigned t2 = (unsigned)x[g];
            unsigned t1 = (s >= 1) ? (unsigned)x[g - 1] : 0u;
            unsigned t0 = (s >= 2) ? (unsigned)x[g - 2] : 0u;
            int e2 = (int)((t1 << BASE_BITS) | t2);
            int e3 = (int)((((t0 << BASE_BITS) | t1) << BASE_BITS) | t2);
            out[g]         = bprobe((const int*)k2v, (const int*)v2v, n2, e2);
            out[total + g] = bprobe((const int*)k3v, (const int*)v3v, n3, e3);
        }
        return;
    }

    // ---------- hash fast path ----------
    const int* x = (const int*)xv;
    iv4 xq = __builtin_nontemporal_load(&((const iv4*)x)[gid]);
    int sb = base & (S - 1);
    unsigned t[6];
    t[0] = (sb != 0) ? (unsigned)x[base - 2] : 0u;
    t[1] = (sb != 0) ? (unsigned)x[base - 1] : 0u;
    t[2] = (unsigned)xq.x; t[3] = (unsigned)xq.y;
    t[4] = (unsigned)xq.z; t[5] = (unsigned)xq.w;

    unsigned e[8], b[8];
    #pragma unroll
    for (int i = 0; i < 4; ++i) {
        unsigned t0 = t[i], t1 = t[i + 1], t2 = t[i + 2];
        e[i]     = (t1 << BASE_BITS) | t2;                        // 2-gram
        e[i + 4] = (((t0 << BASE_BITS) | t1) << BASE_BITS) | t2;  // 3-gram
    }
    #pragma unroll
    for (int i = 0; i < 8; ++i) b[i] = bucket_of(e[i]);

    const uv4* KB2 = (const uv4*)K2;
    const uv4* KB3 = (const uv4*)K3;

    // All 8 home-bucket gathers in flight with ONE asm block.
    const uv4* a0 = KB2 + b[0]; const uv4* a1 = KB2 + b[1];
    const uv4* a2 = KB2 + b[2]; const uv4* a3 = KB2 + b[3];
    const uv4* a4 = KB3 + b[4]; const uv4* a5 = KB3 + b[5];
    const uv4* a6 = KB3 + b[6]; const uv4* a7 = KB3 + b[7];
    uv4 q0, q1, q2, q3, q4, q5, q6, q7;
    asm volatile(
        "global_load_dwordx4 %0, %8, off\n\t"
        "global_load_dwordx4 %1, %9, off\n\t"
        "global_load_dwordx4 %2, %10, off\n\t"
        "global_load_dwordx4 %3, %11, off\n\t"
        "global_load_dwordx4 %4, %12, off\n\t"
        "global_load_dwordx4 %5, %13, off\n\t"
        "global_load_dwordx4 %6, %14, off\n\t"
        "global_load_dwordx4 %7, %15, off\n\t"
        "s_waitcnt vmcnt(0)"
        : "=&v"(q0), "=&v"(q1), "=&v"(q2), "=&v"(q3),
          "=&v"(q4), "=&v"(q5), "=&v"(q6), "=&v"(q7)
        : "v"(a0), "v"(a1), "v"(a2), "v"(a3),
          "v"(a4), "v"(a5), "v"(a6), "v"(a7)
        : "memory");

    int st[8];
    st[0] = match4(q0, e[0], b[0]);
    st[1] = match4(q1, e[1], b[1]);
    st[2] = match4(q2, e[2], b[2]);
    st[3] = match4(q3, e[3], b[3]);
    st[4] = match4(q4, e[4], b[4]);
    st[5] = match4(q5, e[5], b[5]);
    st[6] = match4(q6, e[6], b[6]);
    st[7] = match4(q7, e[7], b[7]);

    // Rare retry loop (bucket overflow continuations), window-wrapped.
    bool cont = false;
    #pragma unroll
    for (int i = 0; i < 8; ++i) cont |= (st[i] == -1);
    while (__any(cont)) {
        #pragma unroll
        for (int i = 0; i < 8; ++i) {
            if (st[i] == -1) {
                b[i] = bnext(b[i]);
                uv4 nq = (i < 4 ? KB2 : KB3)[b[i]];
                st[i] = match4(nq, e[i], b[i]);
            }
        }
        cont = false;
        #pragma unroll
        for (int i = 0; i < 8; ++i) cont |= (st[i] == -1);
    }

    // Predicated value loads (hits ~2.4%).
    int r[8];
    #pragma unroll
    for (int i = 0; i < 8; ++i)
        r[i] = (st[i] >= 0) ? (i < 4 ? V2 : V3)[st[i]] : 0;

    iv4 o2 = { r[0], r[1], r[2], r[3] };
    iv4 o3 = { r[4], r[5], r[6], r[7] };
    __builtin_nontemporal_store(o2, &((iv4*)outv)[gid]);
    __builtin_nontemporal_store(o3, &((iv4*)outv)[total / 4 + gid]);
}

extern "C" void kernel_launch(void* const* d_in, const int* in_sizes, int n_in,
                              void* d_out, int out_size, void* d_ws, size_t ws_size,
                              hipStream_t stream) {
    const void* x  = d_in[0];
    const void* k2 = d_in[1];
    const void* v2 = d_in[2];
    const void* k3 = d_in[3];
    const void* v3 = d_in[4];
    int n2 = in_sizes[1];
    int n3 = in_sizes[3];
    int total = in_sizes[0];     // B * S = 4,194,304 (divisible by 4)
    int S = 16384;

    int* flags = (int*)d_ws;
    size_t key_bytes = (size_t)NSLOTS * 4;          // 1MB per table
    size_t need = 256 + 4 * key_bytes;              // flags | K2 K3 | V2 V3

    int block = 256;
    int grid = (total / 4 + block - 1) / block;

    if (ws_size >= need) {
        unsigned* K2 = (unsigned*)((char*)d_ws + 256);
        unsigned* K3 = K2 + NSLOTS;
        int* V2 = (int*)(K3 + NSLOTS);
        int* V3 = V2 + NSLOTS;

        // ONE fused node: per-window LDS build, no global clear, no dev atomics.
        fused_build_kernel<<<NB, 256, 0, stream>>>(
            (const int*)k2, (const int*)v2, n2,
            (const int*)k3, (const int*)v3, n3,
            (const unsigned*)x, K2, V2, K3, V3, flags);

        ngram_hash_kernel<<<grid, block, 0, stream>>>(
            x, K2, V2, K3, V3, k2, v2, k3, v3, d_out, n2, n3, S, total, flags);
    } else {
        // ws too small for tables: detect dtype, force bsearch path
        detect_dtype_kernel<<<1, 256, 0, stream>>>((const unsigned*)x, flags);
        ngram_hash_kernel<<<grid, block, 0, stream>>>(
            x, nullptr, nullptr, nullptr, nullptr,
            k2, v2, k3, v3, d_out, n2, n3, S, total, flags);
    }
}

// Round 15
// 86.479 us; speedup vs baseline: 4.5048x; 4.5048x over previous
//
#include <hip/hip_runtime.h>

#define BASE_BITS 17
#define BUCKET_LOG 16
#define NBUCKETS (1u << BUCKET_LOG)          // 65536 buckets x 4 slots = 1MB/table
#define NSLOTS (NBUCKETS * 4u)
#define SLOT_MASK (NSLOTS - 1u)
#define BUCKET_MASK (NBUCKETS - 1u)
#define EMPTY 0xFFFFFFFFu

typedef int  iv4 __attribute__((ext_vector_type(4)));
typedef unsigned uv4 __attribute__((ext_vector_type(4)));

__device__ __forceinline__ unsigned bucket_of(unsigned k) {
    return (k * 2654435761u) >> (32 - BUCKET_LOG);
}

// Pure-register bucket match; >=0 hit slot, -2 miss, -1 continue.
__device__ __forceinline__ int match4(uv4 q, unsigned e, unsigned b) {
    int slot = -1;
    slot = (q.w == e) ? (int)(b * 4u + 3u) : slot;
    slot = (q.z == e) ? (int)(b * 4u + 2u) : slot;
    slot = (q.y == e) ? (int)(b * 4u + 1u) : slot;
    slot = (q.x == e) ? (int)(b * 4u + 0u) : slot;
    if (slot >= 0) return slot;
    unsigned mx = max(max(q.x, q.y), max(q.z, q.w));  // EMPTY is max u32
    return (mx == EMPTY) ? -2 : -1;
}

// ---------------- clear: one uv4 per thread (512 x 256 covers 2MB+256B) ----
__global__ void clear_tables_kernel(uv4* __restrict__ dst, unsigned n4) {
    unsigned i = blockIdx.x * blockDim.x + threadIdx.x;
    unsigned stride = gridDim.x * blockDim.x;
    uv4 ones = { EMPTY, EMPTY, EMPTY, EMPTY };
    for (; i < n4; i += stride) dst[i] = ones;
}

// Flags semantics (after 0xFF clear):
//   flags[0] != 0 => int64 input layout ; flags[1] == 0 => force bsearch
__global__ void detect_dtype_kernel(const unsigned* __restrict__ xw,
                                    int* __restrict__ flags) {
    __shared__ int nz;
    if (threadIdx.x == 0) nz = 0;
    __syncthreads();
    if (xw[2 * threadIdx.x + 1] != 0u) atomicOr(&nz, 1);
    __syncthreads();
    if (threadIdx.x == 0) { flags[0] = nz ? 0 : ~0; flags[1] = 0; }
}

// ---------------- build (with inline dtype detect) --------------------------
__global__ void build_hash_kernel(const int* __restrict__ keys2,
                                  const int* __restrict__ vals2, int n2,
                                  const int* __restrict__ keys3,
                                  const int* __restrict__ vals3, int n3,
                                  const unsigned* __restrict__ xw,
                                  unsigned* __restrict__ K2, int* __restrict__ V2,
                                  unsigned* __restrict__ K3, int* __restrict__ V3,
                                  int* __restrict__ flags) {
    int i = blockIdx.x * blockDim.x + threadIdx.x;
    if (i < 256 && xw[2 * i + 1] != 0u) atomicAnd(&flags[0], 0);  // int32 layout

    const int* keys; const int* vals; unsigned* K; int* V; int idx;
    if (i < n2)           { keys = keys2; vals = vals2; K = K2; V = V2; idx = i; }
    else if (i < n2 + n3) { keys = keys3; vals = vals3; K = K3; V = V3; idx = i - n2; }
    else return;
    // NT loads: one-shot reads, keep key/val arrays out of L2 (tables want it)
    unsigned k = (unsigned)__builtin_nontemporal_load(&keys[idx]);
    int v = __builtin_nontemporal_load(&vals[idx]);
    if (k == EMPTY) { atomicAnd(&flags[1], 0); return; }  // sentinel collision
    unsigned slot = bucket_of(k) * 4u;
    for (;;) {
        unsigned prev = atomicCAS(&K[slot], EMPTY, k);
        if (prev == EMPTY) { V[slot] = v; break; }
        slot = (slot + 1u) & SLOT_MASK;
    }
}

// ---------------- binary-search fallback helpers ---------------------------
template <typename K>
__device__ __forceinline__ int lower_bound(const K* __restrict__ keys, int n, K key) {
    int lo = 0, hi = n;
    while (lo < hi) {
        int mid = (lo + hi) >> 1;
        if (keys[mid] < key) lo = mid + 1; else hi = mid;
    }
    return lo;
}

template <typename K>
__device__ __forceinline__ K bprobe(const K* __restrict__ keys,
                                    const K* __restrict__ vals, int n, K key) {
    int idx = lower_bound(keys, n, key);
    if (idx >= n) idx = n - 1;
    return (keys[idx] == key) ? vals[idx] : (K)0;
}

// ---------------- main lookup: 4 elems/thread, 8 forced-parallel probes ----
__global__ __launch_bounds__(256) void ngram_hash_kernel(
    const void* __restrict__ xv,
    const unsigned* __restrict__ K2, const int* __restrict__ V2,
    const unsigned* __restrict__ K3, const int* __restrict__ V3,
    const void* __restrict__ k2v, const void* __restrict__ v2v,
    const void* __restrict__ k3v, const void* __restrict__ v3v,
    void* __restrict__ outv,
    int n2, int n3, int S, int total, const int* __restrict__ flags)
{
    int gid = blockIdx.x * blockDim.x + threadIdx.x;
    int base = gid * 4;
    if (base >= total) return;

    // Hoist the x vector load above the flags branch: overlaps the flags
    // load latency. In-bounds for both layouts (int64 array is 2x bytes).
    const int* x = (const int*)xv;
    iv4 xq = __builtin_nontemporal_load(&((const iv4*)x)[gid]);

    int f0 = __builtin_amdgcn_readfirstlane(flags[0]);
    int f1 = __builtin_amdgcn_readfirstlane(flags[1]);

    if (f0 != 0) {
        // int64 layout (x64-enabled harness): binary-search path
        const long long* xl = (const long long*)xv;
        long long* out = (long long*)outv;
        for (int i = 0; i < 4 && base + i < total; ++i) {
            int g = base + i;
            int s = g & (S - 1);
            long long t2 = xl[g];
            long long t1 = (s >= 1) ? xl[g - 1] : 0ll;
            long long t0 = (s >= 2) ? xl[g - 2] : 0ll;
            long long e2 = (t1 << BASE_BITS) | t2;
            long long e3 = (((t0 << BASE_BITS) | t1) << BASE_BITS) | t2;
            out[g]         = bprobe((const long long*)k2v, (const long long*)v2v, n2, e2);
            out[total + g] = bprobe((const long long*)k3v, (const long long*)v3v, n3, e3);
        }
        return;
    }
    if (f1 == 0) {
        // hash tables unusable: int32 binary search
        int* out = (int*)outv;
        for (int i = 0; i < 4 && base + i < total; ++i) {
            int g = base + i;
            int s = g & (S - 1);
            unsigned t2 = (unsigned)x[g];
            unsigned t1 = (s >= 1) ? (unsigned)x[g - 1] : 0u;
            unsigned t0 = (s >= 2) ? (unsigned)x[g - 2] : 0u;
            int e2 = (int)((t1 << BASE_BITS) | t2);
            int e3 = (int)((((t0 << BASE_BITS) | t1) << BASE_BITS) | t2);
            out[g]         = bprobe((const int*)k2v, (const int*)v2v, n2, e2);
            out[total + g] = bprobe((const int*)k3v, (const int*)v3v, n3, e3);
        }
        return;
    }

    // ---------- hash fast path ----------
    int sb = base & (S - 1);
    unsigned t[6];
    t[0] = (sb != 0) ? (unsigned)x[base - 2] : 0u;
    t[1] = (sb != 0) ? (unsigned)x[base - 1] : 0u;
    t[2] = (unsigned)xq.x; t[3] = (unsigned)xq.y;
    t[4] = (unsigned)xq.z; t[5] = (unsigned)xq.w;

    unsigned e[8], b[8];
    #pragma unroll
    for (int i = 0; i < 4; ++i) {
        unsigned t0 = t[i], t1 = t[i + 1], t2 = t[i + 2];
        e[i]     = (t1 << BASE_BITS) | t2;                        // 2-gram
        e[i + 4] = (((t0 << BASE_BITS) | t1) << BASE_BITS) | t2;  // 3-gram
    }
    #pragma unroll
    for (int i = 0; i < 8; ++i) b[i] = bucket_of(e[i]);

    const uv4* KB2 = (const uv4*)K2;
    const uv4* KB3 = (const uv4*)K3;

    // All 8 home-bucket gathers in flight with ONE asm block.
    const uv4* a0 = KB2 + b[0]; const uv4* a1 = KB2 + b[1];
    const uv4* a2 = KB2 + b[2]; const uv4* a3 = KB2 + b[3];
    const uv4* a4 = KB3 + b[4]; const uv4* a5 = KB3 + b[5];
    const uv4* a6 = KB3 + b[6]; const uv4* a7 = KB3 + b[7];
    uv4 q0, q1, q2, q3, q4, q5, q6, q7;
    asm volatile(
        "global_load_dwordx4 %0, %8, off\n\t"
        "global_load_dwordx4 %1, %9, off\n\t"
        "global_load_dwordx4 %2, %10, off\n\t"
        "global_load_dwordx4 %3, %11, off\n\t"
        "global_load_dwordx4 %4, %12, off\n\t"
        "global_load_dwordx4 %5, %13, off\n\t"
        "global_load_dwordx4 %6, %14, off\n\t"
        "global_load_dwordx4 %7, %15, off\n\t"
        "s_waitcnt vmcnt(0)"
        : "=&v"(q0), "=&v"(q1), "=&v"(q2), "=&v"(q3),
          "=&v"(q4), "=&v"(q5), "=&v"(q6), "=&v"(q7)
        : "v"(a0), "v"(a1), "v"(a2), "v"(a3),
          "v"(a4), "v"(a5), "v"(a6), "v"(a7)
        : "memory");

    int st[8];
    st[0] = match4(q0, e[0], b[0]);
    st[1] = match4(q1, e[1], b[1]);
    st[2] = match4(q2, e[2], b[2]);
    st[3] = match4(q3, e[3], b[3]);
    st[4] = match4(q4, e[4], b[4]);
    st[5] = match4(q5, e[5], b[5]);
    st[6] = match4(q6, e[6], b[6]);
    st[7] = match4(q7, e[7], b[7]);

    // Rare retry loop (bucket overflow continuations).
    bool cont = false;
    #pragma unroll
    for (int i = 0; i < 8; ++i) cont |= (st[i] == -1);
    while (__any(cont)) {
        #pragma unroll
        for (int i = 0; i < 8; ++i) {
            if (st[i] == -1) {
                b[i] = (b[i] + 1u) & BUCKET_MASK;
                uv4 nq = (i < 4 ? KB2 : KB3)[b[i]];
                st[i] = match4(nq, e[i], b[i]);
            }
        }
        cont = false;
        #pragma unroll
        for (int i = 0; i < 8; ++i) cont |= (st[i] == -1);
    }

    // Predicated value loads (hits ~2.4%).
    int r[8];
    #pragma unroll
    for (int i = 0; i < 8; ++i)
        r[i] = (st[i] >= 0) ? (i < 4 ? V2 : V3)[st[i]] : 0;

    iv4 o2 = { r[0], r[1], r[2], r[3] };
    iv4 o3 = { r[4], r[5], r[6], r[7] };
    __builtin_nontemporal_store(o2, &((iv4*)outv)[gid]);
    __builtin_nontemporal_store(o3, &((iv4*)outv)[total / 4 + gid]);
}

extern "C" void kernel_launch(void* const* d_in, const int* in_sizes, int n_in,
                              void* d_out, int out_size, void* d_ws, size_t ws_size,
                              hipStream_t stream) {
    const void* x  = d_in[0];
    const void* k2 = d_in[1];
    const void* v2 = d_in[2];
    const void* k3 = d_in[3];
    const void* v3 = d_in[4];
    int n2 = in_sizes[1];
    int n3 = in_sizes[3];
    int total = in_sizes[0];     // B * S = 4,194,304 (divisible by 4)
    int S = 16384;

    int* flags = (int*)d_ws;
    size_t key_bytes = (size_t)NSLOTS * 4;          // 1MB per table
    size_t need = 256 + 4 * key_bytes;              // flags | K2 K3 | V2 V3

    int block = 256;
    int grid = (total / 4 + block - 1) / block;

    if (ws_size >= need) {
        unsigned* K2 = (unsigned*)((char*)d_ws + 256);
        unsigned* K3 = K2 + NSLOTS;
        int* V2 = (int*)(K3 + NSLOTS);
        int* V3 = V2 + NSLOTS;

        // Compute-engine clear of flags+keys; 512x256 = one uv4 per thread.
        unsigned clear_n4 = (unsigned)((256 + 2 * key_bytes) / 16);
        clear_tables_kernel<<<512, 256, 0, stream>>>((uv4*)d_ws, clear_n4);

        build_hash_kernel<<<(n2 + n3 + 255) / 256, 256, 0, stream>>>(
            (const int*)k2, (const int*)v2, n2,
            (const int*)k3, (const int*)v3, n3,
            (const unsigned*)x, K2, V2, K3, V3, flags);

        ngram_hash_kernel<<<grid, block, 0, stream>>>(
            x, K2, V2, K3, V3, k2, v2, k3, v3, d_out, n2, n3, S, total, flags);
    } else {
        // ws too small for tables: detect dtype, force bsearch path
        detect_dtype_kernel<<<1, 256, 0, stream>>>((const unsigned*)x, flags);
        ngram_hash_kernel<<<grid, block, 0, stream>>>(
            x, nullptr, nullptr, nullptr, nullptr,
            k2, v2, k3, v3, d_out, n2, n3, S, total, flags);
    }
}